// Round 1
// baseline (462.651 us; speedup 1.0000x reference)
//
#include <hip/hip_runtime.h>

#define N_NODES  50000
#define N_EDGES  600000
#define N_GRAPHS 256
#define DIM      128
#define DOUT     32
#define NEG      0.01f

// ---------------- degree / CSR build ----------------

__global__ void k_zero(int* __restrict__ p, int n) {
    int i = blockIdx.x * 256 + threadIdx.x;
    if (i < n) p[i] = 0;
}

__global__ void k_edge_deg(const int* __restrict__ dst, int* __restrict__ counts, int e_cnt) {
    int e = blockIdx.x * 256 + threadIdx.x;
    if (e < e_cnt) atomicAdd(&counts[dst[e]], 1);
}

__global__ void k_isd(const int* __restrict__ counts, float* __restrict__ isd, int n) {
    int i = blockIdx.x * 256 + threadIdx.x;
    if (i < n) {
        float d = (float)counts[i] + 1.0f;
        isd[i] = rsqrtf(d);
    }
}

__global__ void k_scan1(const int* __restrict__ counts, int* __restrict__ rs,
                        int* __restrict__ bsum, int n) {
    __shared__ int s[256];
    int tid = threadIdx.x;
    int i = blockIdx.x * 256 + tid;
    int v = (i < n) ? counts[i] : 0;
    s[tid] = v;
    __syncthreads();
    for (int off = 1; off < 256; off <<= 1) {
        int t = (tid >= off) ? s[tid - off] : 0;
        __syncthreads();
        s[tid] += t;
        __syncthreads();
    }
    int incl = s[tid];
    if (i < n) rs[i] = incl - v;
    if (tid == 255) bsum[blockIdx.x] = incl;
}

__global__ void k_scan2(int* __restrict__ bsum, int nb) {
    __shared__ int s[256];
    int tid = threadIdx.x;
    int v = (tid < nb) ? bsum[tid] : 0;
    s[tid] = v;
    __syncthreads();
    for (int off = 1; off < 256; off <<= 1) {
        int t = (tid >= off) ? s[tid - off] : 0;
        __syncthreads();
        s[tid] += t;
        __syncthreads();
    }
    if (tid < nb) bsum[tid] = s[tid] - v;
}

__global__ void k_scan3(int* __restrict__ rs, const int* __restrict__ bsum, int n) {
    int i = blockIdx.x * 256 + threadIdx.x;
    if (i < n) rs[i] += bsum[blockIdx.x];
}

__global__ void k_fill(const int* __restrict__ src, const int* __restrict__ dst,
                       const float* __restrict__ isd, const int* __restrict__ rs,
                       int* __restrict__ cursor, int* __restrict__ csr_src,
                       float* __restrict__ coef, int e_cnt) {
    int e = blockIdx.x * 256 + threadIdx.x;
    if (e < e_cnt) {
        int s = src[e], d = dst[e];
        int pos = rs[d] + atomicAdd(&cursor[d], 1);
        csr_src[pos] = s;
        coef[pos] = isd[s] * isd[d];
    }
}

// ---------------- GEMM: Y[n,128] = X[n,128] @ W[128,128] (+bias) ----------------
// 128 rows per block, 256 threads, each thread 8 rows x 8 cols. W in LDS.

__global__ __launch_bounds__(256) void k_gemm(const float* __restrict__ X,
                                              const float* __restrict__ W,
                                              const float* __restrict__ bias,
                                              float* __restrict__ Y, int n) {
    __shared__ float4 Wl[4096];  // 128x128 f32
    int tid = threadIdx.x;
    const float4* W4 = (const float4*)W;
#pragma unroll
    for (int i = 0; i < 16; ++i) Wl[tid + i * 256] = W4[tid + i * 256];
    __syncthreads();

    int tx = tid & 15;        // 16 col groups of 8
    int ty = tid >> 4;        // 16 row groups of 8
    int row0 = blockIdx.x * 128 + ty * 8;
    int c4 = tx * 2;          // float4 index of first 4 cols

    float4 accA[8], accB[8];
#pragma unroll
    for (int r = 0; r < 8; ++r) {
        accA[r] = make_float4(0.f, 0.f, 0.f, 0.f);
        accB[r] = make_float4(0.f, 0.f, 0.f, 0.f);
    }

    for (int k0 = 0; k0 < 128; k0 += 4) {
        float4 xv[8];
#pragma unroll
        for (int r = 0; r < 8; ++r) {
            int rr = row0 + r;
            xv[r] = (rr < n) ? *(const float4*)&X[rr * 128 + k0]
                             : make_float4(0.f, 0.f, 0.f, 0.f);
        }
#pragma unroll
        for (int j = 0; j < 4; ++j) {
            float4 wa = Wl[(k0 + j) * 32 + c4];
            float4 wb = Wl[(k0 + j) * 32 + c4 + 1];
#pragma unroll
            for (int r = 0; r < 8; ++r) {
                float xs = ((const float*)&xv[r])[j];
                accA[r].x += xs * wa.x; accA[r].y += xs * wa.y;
                accA[r].z += xs * wa.z; accA[r].w += xs * wa.w;
                accB[r].x += xs * wb.x; accB[r].y += xs * wb.y;
                accB[r].z += xs * wb.z; accB[r].w += xs * wb.w;
            }
        }
    }

    float4 ba = make_float4(0.f, 0.f, 0.f, 0.f), bb = ba;
    if (bias) {
        ba = *(const float4*)&bias[tx * 8];
        bb = *(const float4*)&bias[tx * 8 + 4];
    }
#pragma unroll
    for (int r = 0; r < 8; ++r) {
        int rr = row0 + r;
        if (rr < n) {
            float4 oa = accA[r], ob = accB[r];
            oa.x += ba.x; oa.y += ba.y; oa.z += ba.z; oa.w += ba.w;
            ob.x += bb.x; ob.y += bb.y; ob.z += bb.z; ob.w += bb.w;
            *(float4*)&Y[rr * 128 + tx * 8] = oa;
            *(float4*)&Y[rr * 128 + tx * 8 + 4] = ob;
        }
    }
}

// ---------------- aggregation (one 64-lane wave per node) ----------------
// OUT[v] = leaky( sum_{e: dst=v} coef_e * HT[src_e] + HT[v]*invdeg[v] + bias )

__global__ __launch_bounds__(256) void k_agg(const float* __restrict__ HT,
                                             const int* __restrict__ csr_src,
                                             const float* __restrict__ coef,
                                             const int* __restrict__ rs,
                                             const int* __restrict__ counts,
                                             const float* __restrict__ isd,
                                             const float* __restrict__ bias,
                                             float* __restrict__ OUT, int n) {
    int node = blockIdx.x * 4 + (threadIdx.x >> 6);
    int lane = threadIdx.x & 63;
    if (node >= n) return;
    const float2* H2 = (const float2*)HT;
    int s0 = rs[node], cnt = counts[node];
    float2 acc = make_float2(0.f, 0.f);
    for (int j = 0; j < cnt; ++j) {
        int s = csr_src[s0 + j];
        float c = coef[s0 + j];
        float2 v = H2[s * 64 + lane];
        acc.x += v.x * c;
        acc.y += v.y * c;
    }
    float is = isd[node];
    float invd = is * is;
    float2 sv = H2[node * 64 + lane];
    float2 b = ((const float2*)bias)[lane];
    float ox = acc.x + sv.x * invd + b.x;
    float oy = acc.y + sv.y * invd + b.y;
    ox = ox > 0.f ? ox : ox * NEG;
    oy = oy > 0.f ? oy : oy * NEG;
    ((float2*)OUT)[node * 64 + lane] = make_float2(ox, oy);
}

// ---------------- pooling ----------------

__global__ void k_bounds(const int* __restrict__ batch, int* __restrict__ gs,
                         int* __restrict__ ge, int n) {
    int i = blockIdx.x * 256 + threadIdx.x;
    if (i < n) {
        int b = batch[i];
        if (i == 0 || batch[i - 1] != b) gs[b] = i;
        if (i == n - 1 || batch[i + 1] != b) ge[b] = i + 1;
    }
}

__global__ void k_pool(const float* __restrict__ A, const int* __restrict__ gs,
                       const int* __restrict__ ge, float* __restrict__ hg) {
    __shared__ float red[128];
    int g = blockIdx.x, c = threadIdx.x;
    int s = gs[g], e = ge[g];
    float acc = 0.f;
    for (int r = s; r < e; ++r) acc += A[r * 128 + c];
    float cnt = (float)(e - s);
    float mean = acc / fmaxf(cnt, 1.f);
    red[c] = mean * mean;
    __syncthreads();
    for (int off = 64; off > 0; off >>= 1) {
        if (c < off) red[c] += red[c + off];
        __syncthreads();
    }
    float norm = sqrtf(red[0]);
    hg[g * 128 + c] = mean / fmaxf(norm, 1e-12f);
}

// ---------------- final MLP: out = leaky(hg@W2+b2) @ W3 + b3 ----------------

__global__ void k_final(const float* __restrict__ hg, const float* __restrict__ W2,
                        const float* __restrict__ b2, const float* __restrict__ W3,
                        const float* __restrict__ b3, float* __restrict__ out) {
    __shared__ float h0[128];
    __shared__ float h1[128];
    int g = blockIdx.x, c = threadIdx.x;
    h0[c] = hg[g * 128 + c];
    __syncthreads();
    float acc = b2[c];
#pragma unroll 8
    for (int k = 0; k < 128; ++k) acc += h0[k] * W2[k * 128 + c];
    acc = acc > 0.f ? acc : acc * NEG;
    h1[c] = acc;
    __syncthreads();
    if (c < DOUT) {
        float a2 = b3[c];
#pragma unroll 8
        for (int k = 0; k < 128; ++k) a2 += h1[k] * W3[k * DOUT + c];
        out[g * DOUT + c] = a2;
    }
}

// ---------------- launch ----------------

extern "C" void kernel_launch(void* const* d_in, const int* in_sizes, int n_in,
                              void* d_out, int out_size, void* d_ws, size_t ws_size,
                              hipStream_t stream) {
    const float* x      = (const float*)d_in[0];
    const int*   ei     = (const int*)d_in[1];   // [2, E] flat
    const int*   batch  = (const int*)d_in[2];
    const float* W_fc1  = (const float*)d_in[3];
    const float* b_fc1  = (const float*)d_in[4];
    const float* W_gc1  = (const float*)d_in[5];
    const float* b_gc1  = (const float*)d_in[6];
    const float* W_gc2  = (const float*)d_in[7];
    const float* b_gc2  = (const float*)d_in[8];
    const float* W_fc2  = (const float*)d_in[9];
    const float* b_fc2  = (const float*)d_in[10];
    const float* W_fc3  = (const float*)d_in[11];
    const float* b_fc3  = (const float*)d_in[12];
    float* out = (float*)d_out;

    const int N = N_NODES, E = N_EDGES;
    const int* e_src = ei;
    const int* e_dst = ei + E;

    char* ws = (char*)d_ws;
    float* A       = (float*)(ws + 0);          // 25,600,000 B
    float* B       = (float*)(ws + 25600000);   // 25,600,000 B
    float* isd     = (float*)(ws + 51200000);   // 200,000 B
    float* coef    = (float*)(ws + 51400000);   // 2,400,000 B
    float* hg      = (float*)(ws + 53800000);   // 131,072 B
    int*   rs      = (int*)  (ws + 53931072);   // 200,000 B
    int*   csr_src = (int*)  (ws + 54131072);   // 2,400,000 B
    int*   bsum    = (int*)  (ws + 56531072);   // 1,024 B
    int*   counts  = (int*)  (ws + 56532096);   // 200,000 B
    int*   cursor  = (int*)  (ws + 56732096);   // 200,000 B
    int*   gs      = (int*)  (ws + 56932096);   // 1,024 B
    int*   ge      = (int*)  (ws + 56933120);   // 1,024 B
    // total: 56,934,144 B

    const int ZN = 50000 + 50000 + 256 + 256;   // counts,cursor,gs,ge contiguous
    const int NB = (N + 255) / 256;             // 196
    const int EB = (E + 255) / 256;

    k_zero<<<(ZN + 255) / 256, 256, 0, stream>>>(counts, ZN);
    k_edge_deg<<<EB, 256, 0, stream>>>(e_dst, counts, E);
    k_isd<<<NB, 256, 0, stream>>>(counts, isd, N);
    k_scan1<<<NB, 256, 0, stream>>>(counts, rs, bsum, N);
    k_scan2<<<1, 256, 0, stream>>>(bsum, NB);
    k_scan3<<<NB, 256, 0, stream>>>(rs, bsum, N);
    k_fill<<<EB, 256, 0, stream>>>(e_src, e_dst, isd, rs, cursor, csr_src, coef, E);

    const int GB = (N + 127) / 128;             // 391
    // hx = x @ W_fc1 + b_fc1
    k_gemm<<<GB, 256, 0, stream>>>(x, W_fc1, b_fc1, A, N);
    // conv1: ht = A @ W_gc1 ; agg -> A
    k_gemm<<<GB, 256, 0, stream>>>(A, W_gc1, nullptr, B, N);
    k_agg<<<(N + 3) / 4, 256, 0, stream>>>(B, csr_src, coef, rs, counts, isd, b_gc1, A, N);
    // conv2
    k_gemm<<<GB, 256, 0, stream>>>(A, W_gc2, nullptr, B, N);
    k_agg<<<(N + 3) / 4, 256, 0, stream>>>(B, csr_src, coef, rs, counts, isd, b_gc2, A, N);

    // pool + normalize + MLP head
    k_bounds<<<NB, 256, 0, stream>>>(batch, gs, ge, N);
    k_pool<<<N_GRAPHS, 128, 0, stream>>>(A, gs, ge, hg);
    k_final<<<N_GRAPHS, 128, 0, stream>>>(hg, W_fc2, b_fc2, W_fc3, b_fc3, out);

    (void)in_sizes; (void)n_in; (void)out_size; (void)ws_size;
}

// Round 2
// 356.844 us; speedup vs baseline: 1.2965x; 1.2965x over previous
//
#include <hip/hip_runtime.h>

#define N_NODES  50000
#define N_EDGES  600000
#define N_GRAPHS 256
#define DIM      128
#define DOUT     32
#define NEG      0.01f

// ---------------- degree / CSR build ----------------

__global__ void k_zero(int* __restrict__ p, int n) {
    int i = blockIdx.x * 256 + threadIdx.x;
    if (i < n) p[i] = 0;
}

__global__ void k_edge_deg(const int* __restrict__ dst, int* __restrict__ counts, int e_cnt) {
    int e = blockIdx.x * 256 + threadIdx.x;
    if (e < e_cnt) atomicAdd(&counts[dst[e]], 1);
}

// scan pass 1: block-local inclusive scan -> exclusive row-start; also isd = rsqrt(deg+1)
__global__ void k_scan1(const int* __restrict__ counts, int* __restrict__ rs,
                        int* __restrict__ bsum, float* __restrict__ isd, int n) {
    __shared__ int s[256];
    int tid = threadIdx.x;
    int i = blockIdx.x * 256 + tid;
    int v = (i < n) ? counts[i] : 0;
    if (i < n) isd[i] = rsqrtf((float)v + 1.0f);
    s[tid] = v;
    __syncthreads();
    for (int off = 1; off < 256; off <<= 1) {
        int t = (tid >= off) ? s[tid - off] : 0;
        __syncthreads();
        s[tid] += t;
        __syncthreads();
    }
    int incl = s[tid];
    if (i < n) rs[i] = incl - v;
    if (tid == 255) bsum[blockIdx.x] = incl;
}

__global__ void k_scan2(int* __restrict__ bsum, int nb) {
    __shared__ int s[256];
    int tid = threadIdx.x;
    int v = (tid < nb) ? bsum[tid] : 0;
    s[tid] = v;
    __syncthreads();
    for (int off = 1; off < 256; off <<= 1) {
        int t = (tid >= off) ? s[tid - off] : 0;
        __syncthreads();
        s[tid] += t;
        __syncthreads();
    }
    if (tid < nb) bsum[tid] = s[tid] - v;
}

__global__ void k_scan3(int* __restrict__ rs, const int* __restrict__ bsum, int n) {
    int i = blockIdx.x * 256 + threadIdx.x;
    if (i < n) rs[i] += bsum[blockIdx.x];
}

__global__ void k_fill(const int* __restrict__ src, const int* __restrict__ dst,
                       const float* __restrict__ isd, const int* __restrict__ rs,
                       int* __restrict__ cursor, int* __restrict__ csr_src,
                       float* __restrict__ coef, int e_cnt) {
    int e = blockIdx.x * 256 + threadIdx.x;
    if (e < e_cnt) {
        int s = src[e], d = dst[e];
        int pos = rs[d] + atomicAdd(&cursor[d], 1);
        csr_src[pos] = s;
        coef[pos] = isd[s] * isd[d];
    }
}

// ---------------- GEMM: Y[n,128] = X[n,128] @ W[128,128] (+bias) ----------------
// 64 rows per block, 256 threads, each thread 4 rows x 8 cols. No LDS: W served
// by L1/L2 broadcast (16 distinct 16B segments per load instr), no barriers.

__global__ __launch_bounds__(256) void k_gemm(const float* __restrict__ X,
                                              const float* __restrict__ W,
                                              const float* __restrict__ bias,
                                              float* __restrict__ Y, int n) {
    int tid = threadIdx.x;
    int tx = tid & 15;        // 16 col groups of 8
    int ty = tid >> 4;        // 16 row groups of 4
    int row0 = blockIdx.x * 64 + ty * 4;
    int c4 = tx * 2;

    const float4* W4 = (const float4*)W;
    const float4* X4 = (const float4*)X;

    // clamped row pointers (loads always valid; stores guarded)
    const float4* xp[4];
#pragma unroll
    for (int r = 0; r < 4; ++r) {
        int rr = row0 + r;
        rr = rr < n ? rr : (n - 1);
        xp[r] = X4 + (size_t)rr * 32;
    }

    float4 accA[4], accB[4];
#pragma unroll
    for (int r = 0; r < 4; ++r) {
        accA[r] = make_float4(0.f, 0.f, 0.f, 0.f);
        accB[r] = make_float4(0.f, 0.f, 0.f, 0.f);
    }

#pragma unroll 4
    for (int k0 = 0; k0 < 128; k0 += 4) {
        float4 xv[4];
#pragma unroll
        for (int r = 0; r < 4; ++r) xv[r] = xp[r][k0 >> 2];
#pragma unroll
        for (int j = 0; j < 4; ++j) {
            float4 wa = W4[(k0 + j) * 32 + c4];
            float4 wb = W4[(k0 + j) * 32 + c4 + 1];
#pragma unroll
            for (int r = 0; r < 4; ++r) {
                float xs = ((const float*)&xv[r])[j];
                accA[r].x += xs * wa.x; accA[r].y += xs * wa.y;
                accA[r].z += xs * wa.z; accA[r].w += xs * wa.w;
                accB[r].x += xs * wb.x; accB[r].y += xs * wb.y;
                accB[r].z += xs * wb.z; accB[r].w += xs * wb.w;
            }
        }
    }

    float4 ba = make_float4(0.f, 0.f, 0.f, 0.f), bb = ba;
    if (bias) {
        ba = *(const float4*)&bias[tx * 8];
        bb = *(const float4*)&bias[tx * 8 + 4];
    }
#pragma unroll
    for (int r = 0; r < 4; ++r) {
        int rr = row0 + r;
        if (rr < n) {
            float4 oa = accA[r], ob = accB[r];
            oa.x += ba.x; oa.y += ba.y; oa.z += ba.z; oa.w += ba.w;
            ob.x += bb.x; ob.y += bb.y; ob.z += bb.z; ob.w += bb.w;
            *(float4*)&Y[(size_t)rr * 128 + tx * 8] = oa;
            *(float4*)&Y[(size_t)rr * 128 + tx * 8 + 4] = ob;
        }
    }
}

// ---------------- aggregation (one 64-lane wave per node) ----------------
// OUT[v] = leaky( sum_{e: dst=v} coef_e * HT[src_e] + HT[v]*invdeg[v] + bias )
// unroll-by-4: 4 gathers in flight per wave.

__global__ __launch_bounds__(256) void k_agg(const float* __restrict__ HT,
                                             const int* __restrict__ csr_src,
                                             const float* __restrict__ coef,
                                             const int* __restrict__ rs,
                                             const int* __restrict__ counts,
                                             const float* __restrict__ isd,
                                             const float* __restrict__ bias,
                                             float* __restrict__ OUT, int n) {
    int node = blockIdx.x * 4 + (threadIdx.x >> 6);
    int lane = threadIdx.x & 63;
    if (node >= n) return;
    const float2* H2 = (const float2*)HT;
    int s0 = rs[node], cnt = counts[node];

    // issue self-loop + bias loads early
    float is = isd[node];
    float2 sv = H2[(size_t)node * 64 + lane];
    float2 b = ((const float2*)bias)[lane];

    float2 acc0 = make_float2(0.f, 0.f);
    float2 acc1 = make_float2(0.f, 0.f);
    int j = 0;
    for (; j + 4 <= cnt; j += 4) {
        int base = s0 + j;
        int sA = csr_src[base + 0];
        int sB = csr_src[base + 1];
        int sC = csr_src[base + 2];
        int sD = csr_src[base + 3];
        float cA = coef[base + 0];
        float cB = coef[base + 1];
        float cC = coef[base + 2];
        float cD = coef[base + 3];
        float2 vA = H2[(size_t)sA * 64 + lane];
        float2 vB = H2[(size_t)sB * 64 + lane];
        float2 vC = H2[(size_t)sC * 64 + lane];
        float2 vD = H2[(size_t)sD * 64 + lane];
        acc0.x += vA.x * cA; acc0.y += vA.y * cA;
        acc1.x += vB.x * cB; acc1.y += vB.y * cB;
        acc0.x += vC.x * cC; acc0.y += vC.y * cC;
        acc1.x += vD.x * cD; acc1.y += vD.y * cD;
    }
    for (; j < cnt; ++j) {
        int s = csr_src[s0 + j];
        float c = coef[s0 + j];
        float2 v = H2[(size_t)s * 64 + lane];
        acc0.x += v.x * c; acc0.y += v.y * c;
    }

    float invd = is * is;
    float ox = acc0.x + acc1.x + sv.x * invd + b.x;
    float oy = acc0.y + acc1.y + sv.y * invd + b.y;
    ox = ox > 0.f ? ox : ox * NEG;
    oy = oy > 0.f ? oy : oy * NEG;
    ((float2*)OUT)[(size_t)node * 64 + lane] = make_float2(ox, oy);
}

// ---------------- pooling bounds ----------------

__global__ void k_bounds(const int* __restrict__ batch, int* __restrict__ gs,
                         int* __restrict__ ge, int n) {
    int i = blockIdx.x * 256 + threadIdx.x;
    if (i < n) {
        int b = batch[i];
        if (i == 0 || batch[i - 1] != b) gs[b] = i;
        if (i == n - 1 || batch[i + 1] != b) ge[b] = i + 1;
    }
}

// ---------------- fused pool + L2-normalize + MLP head ----------------

__global__ __launch_bounds__(256) void k_pool_final(const float* __restrict__ A,
                                                    const int* __restrict__ gs,
                                                    const int* __restrict__ ge,
                                                    const float* __restrict__ W2,
                                                    const float* __restrict__ b2,
                                                    const float* __restrict__ W3,
                                                    const float* __restrict__ b3,
                                                    float* __restrict__ out) {
    __shared__ float part[2][128];
    __shared__ float red[128];
    __shared__ float h1[128];
    int g = blockIdx.x, tid = threadIdx.x;
    int c = tid & 127, rr = tid >> 7;
    int s = gs[g], e = ge[g];
    float acc = 0.f;
    for (int r = s + rr; r < e; r += 2) acc += A[(size_t)r * 128 + c];
    part[rr][c] = acc;
    __syncthreads();
    float mean = 0.f;
    if (tid < 128) {
        mean = (part[0][tid] + part[1][tid]) / fmaxf((float)(e - s), 1.f);
        red[tid] = mean * mean;
    }
    __syncthreads();
    for (int off = 64; off > 0; off >>= 1) {
        if (tid < off) red[tid] += red[tid + off];
        __syncthreads();
    }
    if (tid < 128) {
        float norm = sqrtf(red[0]);
        part[0][tid] = mean / fmaxf(norm, 1e-12f);
    }
    __syncthreads();
    if (tid < 128) {
        float a = b2[tid];
#pragma unroll 8
        for (int k = 0; k < 128; ++k) a += part[0][k] * W2[k * 128 + tid];
        a = a > 0.f ? a : a * NEG;
        h1[tid] = a;
    }
    __syncthreads();
    if (tid < DOUT) {
        float a2 = b3[tid];
#pragma unroll 8
        for (int k = 0; k < 128; ++k) a2 += h1[k] * W3[k * DOUT + tid];
        out[g * DOUT + tid] = a2;
    }
}

// ---------------- launch ----------------

extern "C" void kernel_launch(void* const* d_in, const int* in_sizes, int n_in,
                              void* d_out, int out_size, void* d_ws, size_t ws_size,
                              hipStream_t stream) {
    const float* x      = (const float*)d_in[0];
    const int*   ei     = (const int*)d_in[1];   // [2, E] flat
    const int*   batch  = (const int*)d_in[2];
    const float* W_fc1  = (const float*)d_in[3];
    const float* b_fc1  = (const float*)d_in[4];
    const float* W_gc1  = (const float*)d_in[5];
    const float* b_gc1  = (const float*)d_in[6];
    const float* W_gc2  = (const float*)d_in[7];
    const float* b_gc2  = (const float*)d_in[8];
    const float* W_fc2  = (const float*)d_in[9];
    const float* b_fc2  = (const float*)d_in[10];
    const float* W_fc3  = (const float*)d_in[11];
    const float* b_fc3  = (const float*)d_in[12];
    float* out = (float*)d_out;

    const int N = N_NODES, E = N_EDGES;
    const int* e_src = ei;
    const int* e_dst = ei + E;

    char* ws = (char*)d_ws;
    float* A       = (float*)(ws + 0);          // 25,600,000 B
    float* B       = (float*)(ws + 25600000);   // 25,600,000 B
    float* isd     = (float*)(ws + 51200000);   // 200,000 B
    float* coef    = (float*)(ws + 51400000);   // 2,400,000 B
    int*   rs      = (int*)  (ws + 53931072);   // 200,000 B
    int*   csr_src = (int*)  (ws + 54131072);   // 2,400,000 B
    int*   bsum    = (int*)  (ws + 56531072);   // 1,024 B
    int*   counts  = (int*)  (ws + 56532096);   // 200,000 B
    int*   cursor  = (int*)  (ws + 56732096);   // 200,000 B
    int*   gs      = (int*)  (ws + 56932096);   // 1,024 B
    int*   ge      = (int*)  (ws + 56933120);   // 1,024 B
    // total: 56,934,144 B

    const int ZN = 50000 + 50000 + 256 + 256;   // counts,cursor,gs,ge contiguous
    const int NB = (N + 255) / 256;             // 196
    const int EB = (E + 255) / 256;

    k_zero<<<(ZN + 255) / 256, 256, 0, stream>>>(counts, ZN);
    k_edge_deg<<<EB, 256, 0, stream>>>(e_dst, counts, E);
    k_scan1<<<NB, 256, 0, stream>>>(counts, rs, bsum, isd, N);
    k_scan2<<<1, 256, 0, stream>>>(bsum, NB);
    k_scan3<<<NB, 256, 0, stream>>>(rs, bsum, N);
    k_fill<<<EB, 256, 0, stream>>>(e_src, e_dst, isd, rs, cursor, csr_src, coef, E);
    k_bounds<<<NB, 256, 0, stream>>>(batch, gs, ge, N);

    const int GB = (N + 63) / 64;               // 782
    // hx = x @ W_fc1 + b_fc1
    k_gemm<<<GB, 256, 0, stream>>>(x, W_fc1, b_fc1, A, N);
    // conv1: ht = A @ W_gc1 ; agg -> A
    k_gemm<<<GB, 256, 0, stream>>>(A, W_gc1, nullptr, B, N);
    k_agg<<<(N + 3) / 4, 256, 0, stream>>>(B, csr_src, coef, rs, counts, isd, b_gc1, A, N);
    // conv2
    k_gemm<<<GB, 256, 0, stream>>>(A, W_gc2, nullptr, B, N);
    k_agg<<<(N + 3) / 4, 256, 0, stream>>>(B, csr_src, coef, rs, counts, isd, b_gc2, A, N);

    // pool + normalize + MLP head (fused)
    k_pool_final<<<N_GRAPHS, 256, 0, stream>>>(A, gs, ge, W_fc2, b_fc2, W_fc3, b_fc3, out);

    (void)in_sizes; (void)n_in; (void)out_size; (void)ws_size;
}

// Round 3
// 266.040 us; speedup vs baseline: 1.7390x; 1.3413x over previous
//
#include <hip/hip_runtime.h>

#define N_NODES  50000
#define N_EDGES  600000
#define N_GRAPHS 256
#define DIM      128
#define DOUT     32
#define NEG      0.01f

typedef __attribute__((ext_vector_type(8))) short short8;
typedef __attribute__((ext_vector_type(4))) float f32x4;

// ---------------- degree / CSR build ----------------

__global__ void k_zero(int* __restrict__ p, int n) {
    int i = blockIdx.x * 256 + threadIdx.x;
    if (i < n) p[i] = 0;
}

__global__ void k_edge_deg(const int* __restrict__ dst, int* __restrict__ counts, int e_cnt) {
    int e = blockIdx.x * 256 + threadIdx.x;
    if (e < e_cnt) atomicAdd(&counts[dst[e]], 1);
}

// scan pass 1: block-local inclusive scan -> exclusive row-start; also isd = rsqrt(deg+1)
__global__ void k_scan1(const int* __restrict__ counts, int* __restrict__ rs,
                        int* __restrict__ bsum, float* __restrict__ isd, int n) {
    __shared__ int s[256];
    int tid = threadIdx.x;
    int i = blockIdx.x * 256 + tid;
    int v = (i < n) ? counts[i] : 0;
    if (i < n) isd[i] = rsqrtf((float)v + 1.0f);
    s[tid] = v;
    __syncthreads();
    for (int off = 1; off < 256; off <<= 1) {
        int t = (tid >= off) ? s[tid - off] : 0;
        __syncthreads();
        s[tid] += t;
        __syncthreads();
    }
    int incl = s[tid];
    if (i < n) rs[i] = incl - v;
    if (tid == 255) bsum[blockIdx.x] = incl;
}

__global__ void k_scan2(int* __restrict__ bsum, int nb) {
    __shared__ int s[256];
    int tid = threadIdx.x;
    int v = (tid < nb) ? bsum[tid] : 0;
    s[tid] = v;
    __syncthreads();
    for (int off = 1; off < 256; off <<= 1) {
        int t = (tid >= off) ? s[tid - off] : 0;
        __syncthreads();
        s[tid] += t;
        __syncthreads();
    }
    if (tid < nb) bsum[tid] = s[tid] - v;
}

__global__ void k_scan3(int* __restrict__ rs, const int* __restrict__ bsum, int n) {
    int i = blockIdx.x * 256 + threadIdx.x;
    if (i < n) rs[i] += bsum[blockIdx.x];
}

__global__ void k_fill(const int* __restrict__ src, const int* __restrict__ dst,
                       const float* __restrict__ isd, const int* __restrict__ rs,
                       int* __restrict__ cursor, int* __restrict__ csr_src,
                       float* __restrict__ coef, int e_cnt) {
    int e = blockIdx.x * 256 + threadIdx.x;
    if (e < e_cnt) {
        int s = src[e], d = dst[e];
        int pos = rs[d] + atomicAdd(&cursor[d], 1);
        csr_src[pos] = s;
        coef[pos] = isd[s] * isd[d];
    }
}

// ---------------- W pre-pack: fp32 -> bf16 hi/lo in MFMA B-fragment order ---
// Fragment order for mfma_f32_16x16x32_bf16 B-operand:
//   k_tile = k>>5, n_tile = n>>4, lane = ((k&31)>>3)*16 + (n&15), elem = k&7
//   short offset = ((k_tile*8 + n_tile)*64 + lane)*8 + elem
// Per matrix: hi[16384] then lo[16384] shorts (64 KB total).

__device__ __forceinline__ unsigned short bf16_rne(float x) {
    unsigned int u = __float_as_uint(x);
    return (unsigned short)((u + 0x7FFFu + ((u >> 16) & 1u)) >> 16);
}

__global__ void k_pack_w3(const float* __restrict__ W0, const float* __restrict__ W1,
                          const float* __restrict__ W2, short* __restrict__ base) {
    int m = blockIdx.x >> 6;                 // 0..2
    int idx = (blockIdx.x & 63) * 256 + threadIdx.x;   // 0..16383
    const float* W = (m == 0) ? W0 : (m == 1) ? W1 : W2;
    float w = W[idx];
    unsigned short h = bf16_rne(w);
    float hf = __uint_as_float((unsigned int)h << 16);
    unsigned short l = bf16_rne(w - hf);
    int k = idx >> 7, n = idx & 127;
    int kt = k >> 5, nt = n >> 4;
    int lane = ((k & 31) >> 3) * 16 + (n & 15);
    int e = k & 7;
    int off = ((kt * 8 + nt) * 64 + lane) * 8 + e;
    short* hi = base + m * 32768;
    hi[off] = (short)h;
    hi[16384 + off] = (short)l;
}

// ---------------- MFMA GEMM: Y[n,128] = X[n,128] @ W[128,128] (+bias) --------
// Split-bf16: X = hi + lo; Y = hi*Whi + hi*Wlo + lo*Whi (fp32 accum).
// 256 threads = 4 waves, each wave 16 rows x 128 cols. No LDS.

__global__ __launch_bounds__(256) void k_gemm_mfma(
    const float* __restrict__ X,
    const short* __restrict__ Wpk,   // hi[16384] then lo[16384]
    const float* __restrict__ bias,
    float* __restrict__ Y, int n)
{
    int wid = threadIdx.x >> 6;
    int lane = threadIdx.x & 63;
    int r0 = blockIdx.x * 64 + wid * 16;
    int arow = r0 + (lane & 15);
    if (arow >= n) arow = n - 1;             // clamp loads; stores guarded
    int kb = (lane >> 4) * 8;                // k offset in 32-tile: 0,8,16,24

    const float4* xp = (const float4*)(X + (size_t)arow * 128);
    const short8* WH = (const short8*)Wpk;
    const short8* WL = (const short8*)(Wpk + 16384);

    f32x4 acc[8];
    f32x4 zero = {0.f, 0.f, 0.f, 0.f};
#pragma unroll
    for (int t = 0; t < 8; ++t) acc[t] = zero;

#pragma unroll
    for (int kt = 0; kt < 4; ++kt) {
        int f4 = kt * 8 + (kb >> 2);
        float4 x0 = xp[f4];
        float4 x1 = xp[f4 + 1];
        float xs[8] = {x0.x, x0.y, x0.z, x0.w, x1.x, x1.y, x1.z, x1.w};
        short8 ahi, alo;
#pragma unroll
        for (int i = 0; i < 8; ++i) {
            unsigned short h = bf16_rne(xs[i]);
            float hf = __uint_as_float((unsigned int)h << 16);
            unsigned short l = bf16_rne(xs[i] - hf);
            ahi[i] = (short)h;
            alo[i] = (short)l;
        }
#pragma unroll
        for (int t = 0; t < 8; ++t) {
            int fo = (kt * 8 + t) * 64 + lane;
            short8 bh = WH[fo];
            short8 bl = WL[fo];
            acc[t] = __builtin_amdgcn_mfma_f32_16x16x32_bf16(ahi, bh, acc[t], 0, 0, 0);
            acc[t] = __builtin_amdgcn_mfma_f32_16x16x32_bf16(ahi, bl, acc[t], 0, 0, 0);
            acc[t] = __builtin_amdgcn_mfma_f32_16x16x32_bf16(alo, bh, acc[t], 0, 0, 0);
        }
    }

    // C/D layout: col = t*16 + (lane&15), row = r0 + (lane>>4)*4 + reg
    int rbase = r0 + (lane >> 4) * 4;
    int col0 = lane & 15;
#pragma unroll
    for (int t = 0; t < 8; ++t) {
        int col = t * 16 + col0;
        float badd = bias ? bias[col] : 0.f;
#pragma unroll
        for (int r = 0; r < 4; ++r) {
            int row = rbase + r;
            if (row < n) Y[(size_t)row * 128 + col] = acc[t][r] + badd;
        }
    }
}

// ---------------- aggregation (one 64-lane wave per node) ----------------
// OUT[v] = leaky( sum_{e: dst=v} coef_e * HT[src_e] + HT[v]*invdeg[v] + bias )

__global__ __launch_bounds__(256) void k_agg(const float* __restrict__ HT,
                                             const int* __restrict__ csr_src,
                                             const float* __restrict__ coef,
                                             const int* __restrict__ rs,
                                             const int* __restrict__ counts,
                                             const float* __restrict__ isd,
                                             const float* __restrict__ bias,
                                             float* __restrict__ OUT, int n) {
    int node = blockIdx.x * 4 + (threadIdx.x >> 6);
    int lane = threadIdx.x & 63;
    if (node >= n) return;
    const float2* H2 = (const float2*)HT;
    int s0 = rs[node], cnt = counts[node];

    float is = isd[node];
    float2 sv = H2[(size_t)node * 64 + lane];
    float2 b = ((const float2*)bias)[lane];

    float2 acc0 = make_float2(0.f, 0.f);
    float2 acc1 = make_float2(0.f, 0.f);
    int j = 0;
    for (; j + 4 <= cnt; j += 4) {
        int base = s0 + j;
        int sA = csr_src[base + 0];
        int sB = csr_src[base + 1];
        int sC = csr_src[base + 2];
        int sD = csr_src[base + 3];
        float cA = coef[base + 0];
        float cB = coef[base + 1];
        float cC = coef[base + 2];
        float cD = coef[base + 3];
        float2 vA = H2[(size_t)sA * 64 + lane];
        float2 vB = H2[(size_t)sB * 64 + lane];
        float2 vC = H2[(size_t)sC * 64 + lane];
        float2 vD = H2[(size_t)sD * 64 + lane];
        acc0.x += vA.x * cA; acc0.y += vA.y * cA;
        acc1.x += vB.x * cB; acc1.y += vB.y * cB;
        acc0.x += vC.x * cC; acc0.y += vC.y * cC;
        acc1.x += vD.x * cD; acc1.y += vD.y * cD;
    }
    for (; j < cnt; ++j) {
        int s = csr_src[s0 + j];
        float c = coef[s0 + j];
        float2 v = H2[(size_t)s * 64 + lane];
        acc0.x += v.x * c; acc0.y += v.y * c;
    }

    float invd = is * is;
    float ox = acc0.x + acc1.x + sv.x * invd + b.x;
    float oy = acc0.y + acc1.y + sv.y * invd + b.y;
    ox = ox > 0.f ? ox : ox * NEG;
    oy = oy > 0.f ? oy : oy * NEG;
    ((float2*)OUT)[(size_t)node * 64 + lane] = make_float2(ox, oy);
}

// ---------------- pooling bounds ----------------

__global__ void k_bounds(const int* __restrict__ batch, int* __restrict__ gs,
                         int* __restrict__ ge, int n) {
    int i = blockIdx.x * 256 + threadIdx.x;
    if (i < n) {
        int b = batch[i];
        if (i == 0 || batch[i - 1] != b) gs[b] = i;
        if (i == n - 1 || batch[i + 1] != b) ge[b] = i + 1;
    }
}

// ---------------- fused pool + L2-normalize + MLP head ----------------

__global__ __launch_bounds__(256) void k_pool_final(const float* __restrict__ A,
                                                    const int* __restrict__ gs,
                                                    const int* __restrict__ ge,
                                                    const float* __restrict__ W2,
                                                    const float* __restrict__ b2,
                                                    const float* __restrict__ W3,
                                                    const float* __restrict__ b3,
                                                    float* __restrict__ out) {
    __shared__ float part[2][128];
    __shared__ float red[128];
    __shared__ float h1[128];
    int g = blockIdx.x, tid = threadIdx.x;
    int c = tid & 127, rr = tid >> 7;
    int s = gs[g], e = ge[g];
    float acc = 0.f;
    for (int r = s + rr; r < e; r += 2) acc += A[(size_t)r * 128 + c];
    part[rr][c] = acc;
    __syncthreads();
    float mean = 0.f;
    if (tid < 128) {
        mean = (part[0][tid] + part[1][tid]) / fmaxf((float)(e - s), 1.f);
        red[tid] = mean * mean;
    }
    __syncthreads();
    for (int off = 64; off > 0; off >>= 1) {
        if (tid < off) red[tid] += red[tid + off];
        __syncthreads();
    }
    if (tid < 128) {
        float norm = sqrtf(red[0]);
        part[0][tid] = mean / fmaxf(norm, 1e-12f);
    }
    __syncthreads();
    if (tid < 128) {
        float a = b2[tid];
#pragma unroll 8
        for (int k = 0; k < 128; ++k) a += part[0][k] * W2[k * 128 + tid];
        a = a > 0.f ? a : a * NEG;
        h1[tid] = a;
    }
    __syncthreads();
    if (tid < DOUT) {
        float a2 = b3[tid];
#pragma unroll 8
        for (int k = 0; k < 128; ++k) a2 += h1[k] * W3[k * DOUT + tid];
        out[g * DOUT + tid] = a2;
    }
}

// ---------------- launch ----------------

extern "C" void kernel_launch(void* const* d_in, const int* in_sizes, int n_in,
                              void* d_out, int out_size, void* d_ws, size_t ws_size,
                              hipStream_t stream) {
    const float* x      = (const float*)d_in[0];
    const int*   ei     = (const int*)d_in[1];   // [2, E] flat
    const int*   batch  = (const int*)d_in[2];
    const float* W_fc1  = (const float*)d_in[3];
    const float* b_fc1  = (const float*)d_in[4];
    const float* W_gc1  = (const float*)d_in[5];
    const float* b_gc1  = (const float*)d_in[6];
    const float* W_gc2  = (const float*)d_in[7];
    const float* b_gc2  = (const float*)d_in[8];
    const float* W_fc2  = (const float*)d_in[9];
    const float* b_fc2  = (const float*)d_in[10];
    const float* W_fc3  = (const float*)d_in[11];
    const float* b_fc3  = (const float*)d_in[12];
    float* out = (float*)d_out;

    const int N = N_NODES, E = N_EDGES;
    const int* e_src = ei;
    const int* e_dst = ei + E;

    char* ws = (char*)d_ws;
    float* A       = (float*)(ws + 0);          // 25,600,000 B
    float* B       = (float*)(ws + 25600000);   // 25,600,000 B
    float* isd     = (float*)(ws + 51200000);   // 200,000 B
    float* coef    = (float*)(ws + 51400000);   // 2,400,000 B
    int*   rs      = (int*)  (ws + 53800000);   // 200,000 B
    int*   csr_src = (int*)  (ws + 54000000);   // 2,400,000 B
    int*   bsum    = (int*)  (ws + 56400000);   // 1,024 B
    int*   counts  = (int*)  (ws + 56401024);   // 200,000 B
    int*   cursor  = (int*)  (ws + 56601024);   // 200,000 B
    int*   gs      = (int*)  (ws + 56801024);   // 1,024 B
    int*   ge      = (int*)  (ws + 56802048);   // 1,024 B
    short* Wpk     = (short*)(ws + 56803072);   // 196,608 B (3 mats x hi/lo)
    // total: 56,999,680 B

    const int ZN = 50000 + 50000 + 256 + 256;   // counts,cursor,gs,ge contiguous
    const int NB = (N + 255) / 256;             // 196
    const int EB = (E + 255) / 256;

    k_pack_w3<<<192, 256, 0, stream>>>(W_fc1, W_gc1, W_gc2, Wpk);
    k_zero<<<(ZN + 255) / 256, 256, 0, stream>>>(counts, ZN);
    k_edge_deg<<<EB, 256, 0, stream>>>(e_dst, counts, E);
    k_scan1<<<NB, 256, 0, stream>>>(counts, rs, bsum, isd, N);
    k_scan2<<<1, 256, 0, stream>>>(bsum, NB);
    k_scan3<<<NB, 256, 0, stream>>>(rs, bsum, N);
    k_fill<<<EB, 256, 0, stream>>>(e_src, e_dst, isd, rs, cursor, csr_src, coef, E);
    k_bounds<<<NB, 256, 0, stream>>>(batch, gs, ge, N);

    const int GB = (N + 63) / 64;               // 782
    // hx = x @ W_fc1 + b_fc1
    k_gemm_mfma<<<GB, 256, 0, stream>>>(x, Wpk, b_fc1, A, N);
    // conv1: ht = A @ W_gc1 ; agg -> A
    k_gemm_mfma<<<GB, 256, 0, stream>>>(A, Wpk + 32768, nullptr, B, N);
    k_agg<<<(N + 3) / 4, 256, 0, stream>>>(B, csr_src, coef, rs, counts, isd, b_gc1, A, N);
    // conv2
    k_gemm_mfma<<<GB, 256, 0, stream>>>(A, Wpk + 65536, nullptr, B, N);
    k_agg<<<(N + 3) / 4, 256, 0, stream>>>(B, csr_src, coef, rs, counts, isd, b_gc2, A, N);

    // pool + normalize + MLP head (fused)
    k_pool_final<<<N_GRAPHS, 256, 0, stream>>>(A, gs, ge, W_fc2, b_fc2, W_fc3, b_fc3, out);

    (void)in_sizes; (void)n_in; (void)out_size; (void)ws_size;
}

// Round 5
// 213.165 us; speedup vs baseline: 2.1704x; 1.2480x over previous
//
#include <hip/hip_runtime.h>

#define N_NODES  50000
#define N_EDGES  600000
#define N_GRAPHS 256
#define DIM      128
#define DOUT     32
#define NEG      0.01f

typedef __attribute__((ext_vector_type(8))) short short8;
typedef __attribute__((ext_vector_type(4))) float f32x4;

__device__ __forceinline__ unsigned short bf16_rne(float x) {
    unsigned int u = __float_as_uint(x);
    return (unsigned short)((u + 0x7FFFu + ((u >> 16) & 1u)) >> 16);
}

// ---------------- fused W pre-pack + workspace zero ----------------
// blocks [0,192): pack 3 matrices fp32 -> bf16 hi/lo in MFMA B-frag order
// blocks [192,...): zero counts/cursor/gs/ge (100512 ints)

__global__ void k_pack_zero(const float* __restrict__ W0, const float* __restrict__ W1,
                            const float* __restrict__ W2, short* __restrict__ base,
                            int* __restrict__ zp, int zn) {
    int bid = blockIdx.x;
    if (bid < 192) {
        int m = bid >> 6;
        int idx = (bid & 63) * 256 + threadIdx.x;   // 0..16383
        const float* W = (m == 0) ? W0 : (m == 1) ? W1 : W2;
        float w = W[idx];
        unsigned short h = bf16_rne(w);
        float hf = __uint_as_float((unsigned int)h << 16);
        unsigned short l = bf16_rne(w - hf);
        int k = idx >> 7, n = idx & 127;
        int kt = k >> 5, nt = n >> 4;
        int lane = ((k & 31) >> 3) * 16 + (n & 15);
        int e = k & 7;
        int off = ((kt * 8 + nt) * 64 + lane) * 8 + e;
        short* hi = base + m * 32768;
        hi[off] = (short)h;
        hi[16384 + off] = (short)l;
    } else {
        int i = (bid - 192) * 256 + threadIdx.x;
        if (i < zn) zp[i] = 0;
    }
}

// ---------------- degree / CSR build ----------------

__global__ void k_edge_deg(const int* __restrict__ dst, int* __restrict__ counts, int e_cnt) {
    int e = blockIdx.x * 256 + threadIdx.x;
    if (e < e_cnt) atomicAdd(&counts[dst[e]], 1);
}

__global__ void k_scan1(const int* __restrict__ counts, int* __restrict__ rs,
                        int* __restrict__ bsum, float* __restrict__ isd, int n) {
    __shared__ int s[256];
    int tid = threadIdx.x;
    int i = blockIdx.x * 256 + tid;
    int v = (i < n) ? counts[i] : 0;
    if (i < n) isd[i] = rsqrtf((float)v + 1.0f);
    s[tid] = v;
    __syncthreads();
    for (int off = 1; off < 256; off <<= 1) {
        int t = (tid >= off) ? s[tid - off] : 0;
        __syncthreads();
        s[tid] += t;
        __syncthreads();
    }
    int incl = s[tid];
    if (i < n) rs[i] = incl - v;
    if (tid == 255) bsum[blockIdx.x] = incl;
}

__global__ void k_scan2(int* __restrict__ bsum, int nb) {
    __shared__ int s[256];
    int tid = threadIdx.x;
    int v = (tid < nb) ? bsum[tid] : 0;
    s[tid] = v;
    __syncthreads();
    for (int off = 1; off < 256; off <<= 1) {
        int t = (tid >= off) ? s[tid - off] : 0;
        __syncthreads();
        s[tid] += t;
        __syncthreads();
    }
    if (tid < nb) bsum[tid] = s[tid] - v;
}

// scan finalize + pooling bounds (same grid shape)
__global__ void k_scan3b(int* __restrict__ rs, const int* __restrict__ bsum,
                         const int* __restrict__ batch, int* __restrict__ gs,
                         int* __restrict__ ge, int n) {
    int i = blockIdx.x * 256 + threadIdx.x;
    if (i < n) {
        rs[i] += bsum[blockIdx.x];
        int b = batch[i];
        if (i == 0 || batch[i - 1] != b) gs[b] = i;
        if (i == n - 1 || batch[i + 1] != b) ge[b] = i + 1;
    }
}

// CSR entry packed: .x = src index, .y = coef bits
__global__ void k_fill(const int* __restrict__ src, const int* __restrict__ dst,
                       const float* __restrict__ isd, const int* __restrict__ rs,
                       int* __restrict__ cursor, uint2* __restrict__ csr, int e_cnt) {
    int e = blockIdx.x * 256 + threadIdx.x;
    if (e < e_cnt) {
        int s = src[e], d = dst[e];
        int pos = rs[d] + atomicAdd(&cursor[d], 1);
        csr[pos] = make_uint2((unsigned)s, __float_as_uint(isd[s] * isd[d]));
    }
}

// ---------------- MFMA GEMM: Y[n,128] = X[n,128] @ W[128,128] (+bias) --------
// Split-bf16: X = hi + lo; Y = hi*Whi + hi*Wlo + lo*Whi (fp32 accum).
// 256 threads = 4 waves, each wave 16 rows x 128 cols. No LDS.
// OUT_BF16: write Y as bf16 (ushort) row-major instead of fp32.

template <int OUT_BF16>
__global__ __launch_bounds__(256) void k_gemm_mfma(
    const float* __restrict__ X,
    const short* __restrict__ Wpk,   // hi[16384] then lo[16384]
    const float* __restrict__ bias,
    float* __restrict__ Yf, unsigned short* __restrict__ Yh, int n)
{
    int wid = threadIdx.x >> 6;
    int lane = threadIdx.x & 63;
    int r0 = blockIdx.x * 64 + wid * 16;
    int arow = r0 + (lane & 15);
    if (arow >= n) arow = n - 1;             // clamp loads; stores guarded
    int kb = (lane >> 4) * 8;                // k offset in 32-tile: 0,8,16,24

    const float4* xp = (const float4*)(X + (size_t)arow * 128);
    const short8* WH = (const short8*)Wpk;
    const short8* WL = (const short8*)(Wpk + 16384);

    f32x4 acc[8];
    f32x4 zero = {0.f, 0.f, 0.f, 0.f};
#pragma unroll
    for (int t = 0; t < 8; ++t) acc[t] = zero;

#pragma unroll
    for (int kt = 0; kt < 4; ++kt) {
        int f4 = kt * 8 + (kb >> 2);
        float4 x0 = xp[f4];
        float4 x1 = xp[f4 + 1];
        float xs[8] = {x0.x, x0.y, x0.z, x0.w, x1.x, x1.y, x1.z, x1.w};
        short8 ahi, alo;
#pragma unroll
        for (int i = 0; i < 8; ++i) {
            unsigned short h = bf16_rne(xs[i]);
            float hf = __uint_as_float((unsigned int)h << 16);
            unsigned short l = bf16_rne(xs[i] - hf);
            ahi[i] = (short)h;
            alo[i] = (short)l;
        }
#pragma unroll
        for (int t = 0; t < 8; ++t) {
            int fo = (kt * 8 + t) * 64 + lane;
            short8 bh = WH[fo];
            short8 bl = WL[fo];
            acc[t] = __builtin_amdgcn_mfma_f32_16x16x32_bf16(ahi, bh, acc[t], 0, 0, 0);
            acc[t] = __builtin_amdgcn_mfma_f32_16x16x32_bf16(ahi, bl, acc[t], 0, 0, 0);
            acc[t] = __builtin_amdgcn_mfma_f32_16x16x32_bf16(alo, bh, acc[t], 0, 0, 0);
        }
    }

    // C/D layout: col = t*16 + (lane&15), row = r0 + (lane>>4)*4 + reg
    int rbase = r0 + (lane >> 4) * 4;
    int col0 = lane & 15;
#pragma unroll
    for (int t = 0; t < 8; ++t) {
        int col = t * 16 + col0;
        float badd = bias ? bias[col] : 0.f;
#pragma unroll
        for (int r = 0; r < 4; ++r) {
            int row = rbase + r;
            if (row < n) {
                float v = acc[t][r] + badd;
                if (OUT_BF16)
                    Yh[(size_t)row * 128 + col] = bf16_rne(v);
                else
                    Yf[(size_t)row * 128 + col] = v;
            }
        }
    }
}

// ---------------- aggregation (one 64-lane wave per node, bf16 ht) ----------
// OUT[v] = leaky( sum_e coef_e * HT[src_e] + HT[v]*invdeg[v] + bias )  (fp32 out)

__global__ __launch_bounds__(256) void k_agg(const unsigned short* __restrict__ HT,
                                             const uint2* __restrict__ csr,
                                             const int* __restrict__ rs,
                                             const int* __restrict__ counts,
                                             const float* __restrict__ isd,
                                             const float* __restrict__ bias,
                                             float* __restrict__ OUT, int n) {
    int node = blockIdx.x * 4 + (threadIdx.x >> 6);
    int lane = threadIdx.x & 63;
    if (node >= n) return;
    const unsigned int* H = (const unsigned int*)HT;   // row = 64 uints (2 bf16 each)
    int s0 = rs[node], cnt = counts[node];

    float is = isd[node];
    unsigned int su = H[(size_t)node * 64 + lane];
    float2 b = ((const float2*)bias)[lane];

    float acc0 = 0.f, acc1 = 0.f, acc2 = 0.f, acc3 = 0.f;
    int j = 0;
    for (; j + 8 <= cnt; j += 8) {
        uint2 e[8];
#pragma unroll
        for (int q = 0; q < 8; ++q) e[q] = csr[s0 + j + q];
        unsigned int v[8];
#pragma unroll
        for (int q = 0; q < 8; ++q) v[q] = H[(size_t)e[q].x * 64 + lane];
#pragma unroll
        for (int q = 0; q < 8; ++q) {
            float c = __uint_as_float(e[q].y);
            float f0 = __uint_as_float(v[q] << 16);
            float f1 = __uint_as_float(v[q] & 0xFFFF0000u);
            if (q & 1) { acc2 += f0 * c; acc3 += f1 * c; }
            else       { acc0 += f0 * c; acc1 += f1 * c; }
        }
    }
    for (; j + 4 <= cnt; j += 4) {
        uint2 e[4];
#pragma unroll
        for (int q = 0; q < 4; ++q) e[q] = csr[s0 + j + q];
        unsigned int v[4];
#pragma unroll
        for (int q = 0; q < 4; ++q) v[q] = H[(size_t)e[q].x * 64 + lane];
#pragma unroll
        for (int q = 0; q < 4; ++q) {
            float c = __uint_as_float(e[q].y);
            float f0 = __uint_as_float(v[q] << 16);
            float f1 = __uint_as_float(v[q] & 0xFFFF0000u);
            if (q & 1) { acc2 += f0 * c; acc3 += f1 * c; }
            else       { acc0 += f0 * c; acc1 += f1 * c; }
        }
    }
    for (; j < cnt; ++j) {
        uint2 e = csr[s0 + j];
        unsigned int v = H[(size_t)e.x * 64 + lane];
        float c = __uint_as_float(e.y);
        acc0 += __uint_as_float(v << 16) * c;
        acc1 += __uint_as_float(v & 0xFFFF0000u) * c;
    }

    float invd = is * is;
    float sv0 = __uint_as_float(su << 16);
    float sv1 = __uint_as_float(su & 0xFFFF0000u);
    float ox = acc0 + acc2 + sv0 * invd + b.x;
    float oy = acc1 + acc3 + sv1 * invd + b.y;
    ox = ox > 0.f ? ox : ox * NEG;
    oy = oy > 0.f ? oy : oy * NEG;
    ((float2*)OUT)[(size_t)node * 64 + lane] = make_float2(ox, oy);
}

// ---------------- fused pool + L2-normalize + MLP head ----------------

__global__ __launch_bounds__(256) void k_pool_final(const float* __restrict__ A,
                                                    const int* __restrict__ gs,
                                                    const int* __restrict__ ge,
                                                    const float* __restrict__ W2,
                                                    const float* __restrict__ b2,
                                                    const float* __restrict__ W3,
                                                    const float* __restrict__ b3,
                                                    float* __restrict__ out) {
    __shared__ float part[4][128];
    __shared__ float red[128];
    __shared__ float h1[128];
    int g = blockIdx.x, tid = threadIdx.x;
    int c2 = tid & 63, rr = tid >> 6;   // 4 rows per iter, float2 per thread
    int s = gs[g], e = ge[g];
    float2 acc = make_float2(0.f, 0.f);
    const float2* A2 = (const float2*)A;
    for (int r = s + rr; r < e; r += 4) {
        float2 v = A2[(size_t)r * 64 + c2];
        acc.x += v.x; acc.y += v.y;
    }
    part[rr][c2 * 2] = acc.x;
    part[rr][c2 * 2 + 1] = acc.y;
    __syncthreads();
    float mean = 0.f;
    if (tid < 128) {
        mean = (part[0][tid] + part[1][tid] + part[2][tid] + part[3][tid])
               / fmaxf((float)(e - s), 1.f);
        red[tid] = mean * mean;
    }
    __syncthreads();
    for (int off = 64; off > 0; off >>= 1) {
        if (tid < off) red[tid] += red[tid + off];
        __syncthreads();
    }
    if (tid < 128) {
        float norm = sqrtf(red[0]);
        part[0][tid] = mean / fmaxf(norm, 1e-12f);
    }
    __syncthreads();
    if (tid < 128) {
        float a = b2[tid];
#pragma unroll 8
        for (int k = 0; k < 128; ++k) a += part[0][k] * W2[k * 128 + tid];
        a = a > 0.f ? a : a * NEG;
        h1[tid] = a;
    }
    __syncthreads();
    if (tid < DOUT) {
        float a2 = b3[tid];
#pragma unroll 8
        for (int k = 0; k < 128; ++k) a2 += h1[k] * W3[k * DOUT + tid];
        out[g * DOUT + tid] = a2;
    }
}

// ---------------- launch ----------------

extern "C" void kernel_launch(void* const* d_in, const int* in_sizes, int n_in,
                              void* d_out, int out_size, void* d_ws, size_t ws_size,
                              hipStream_t stream) {
    const float* x      = (const float*)d_in[0];
    const int*   ei     = (const int*)d_in[1];   // [2, E] flat
    const int*   batch  = (const int*)d_in[2];
    const float* W_fc1  = (const float*)d_in[3];
    const float* b_fc1  = (const float*)d_in[4];
    const float* W_gc1  = (const float*)d_in[5];
    const float* b_gc1  = (const float*)d_in[6];
    const float* W_gc2  = (const float*)d_in[7];
    const float* b_gc2  = (const float*)d_in[8];
    const float* W_fc2  = (const float*)d_in[9];
    const float* b_fc2  = (const float*)d_in[10];
    const float* W_fc3  = (const float*)d_in[11];
    const float* b_fc3  = (const float*)d_in[12];
    float* out = (float*)d_out;

    const int N = N_NODES, E = N_EDGES;
    const int* e_src = ei;
    const int* e_dst = ei + E;

    // workspace layout (no trailing backslashes in these comments!)
    // A:      off 0,        25,600,000 B
    // Bh:     off 25600000, 12,800,000 B (bf16 ht)
    // isd:    off 38400000,    200,000 B
    // csr:    off 38600000,  4,800,000 B
    // rs:     off 43400000,    200,000 B
    // bsum:   off 43600000,      1,024 B
    // counts: off 43601024,    200,000 B  -- start of contiguous zero region
    // cursor: off 43801024,    200,000 B
    // gs:     off 44001024,      1,024 B
    // ge:     off 44002048,      1,024 B  -- end of zero region
    // Wpk:    off 44003072,    196,608 B
    char* ws = (char*)d_ws;
    float*          A      = (float*)(ws + 0);
    unsigned short* Bh     = (unsigned short*)(ws + 25600000);
    float*          isd    = (float*)(ws + 38400000);
    uint2*          csr    = (uint2*)(ws + 38600000);
    int*            rs     = (int*)  (ws + 43400000);
    int*            bsum   = (int*)  (ws + 43600000);
    int*            counts = (int*)  (ws + 43601024);
    int*            cursor = (int*)  (ws + 43801024);
    int*            gs     = (int*)  (ws + 44001024);
    int*            ge     = (int*)  (ws + 44002048);
    short*          Wpk    = (short*)(ws + 44003072);

    const int ZN = 50000 + 50000 + 256 + 256;   // counts,cursor,gs,ge contiguous
    const int NB = (N + 255) / 256;             // 196
    const int EB = (E + 255) / 256;
    const int ZB = (ZN + 255) / 256;            // 393

    k_pack_zero<<<192 + ZB, 256, 0, stream>>>(W_fc1, W_gc1, W_gc2, Wpk, counts, ZN);
    k_edge_deg<<<EB, 256, 0, stream>>>(e_dst, counts, E);
    k_scan1<<<NB, 256, 0, stream>>>(counts, rs, bsum, isd, N);
    k_scan2<<<1, 256, 0, stream>>>(bsum, NB);
    k_scan3b<<<NB, 256, 0, stream>>>(rs, bsum, batch, gs, ge, N);
    k_fill<<<EB, 256, 0, stream>>>(e_src, e_dst, isd, rs, cursor, csr, E);

    const int GB = (N + 63) / 64;               // 782
    // hx = x @ W_fc1 + b_fc1  (fp32 out -> A)
    k_gemm_mfma<0><<<GB, 256, 0, stream>>>(x, Wpk, b_fc1, A, nullptr, N);
    // conv1: ht = A @ W_gc1 (bf16 out -> Bh); agg -> A
    k_gemm_mfma<1><<<GB, 256, 0, stream>>>(A, Wpk + 32768, nullptr, nullptr, Bh, N);
    k_agg<<<(N + 3) / 4, 256, 0, stream>>>(Bh, csr, rs, counts, isd, b_gc1, A, N);
    // conv2
    k_gemm_mfma<1><<<GB, 256, 0, stream>>>(A, Wpk + 65536, nullptr, nullptr, Bh, N);
    k_agg<<<(N + 3) / 4, 256, 0, stream>>>(Bh, csr, rs, counts, isd, b_gc2, A, N);

    // pool + normalize + MLP head (fused)
    k_pool_final<<<N_GRAPHS, 256, 0, stream>>>(A, gs, ge, W_fc2, b_fc2, W_fc3, b_fc3, out);

    (void)in_sizes; (void)n_in; (void)out_size; (void)ws_size;
}

// Round 6
// 208.057 us; speedup vs baseline: 2.2237x; 1.0245x over previous
//
#include <hip/hip_runtime.h>

#define N_NODES  50000
#define N_EDGES  600000
#define N_GRAPHS 256
#define DOUT     32
#define NEG      0.01f

typedef __attribute__((ext_vector_type(8))) short short8;
typedef __attribute__((ext_vector_type(4))) float f32x4;

__device__ __forceinline__ unsigned short bf16_rne(float x) {
    unsigned int u = __float_as_uint(x);
    return (unsigned short)((u + 0x7FFFu + ((u >> 16) & 1u)) >> 16);
}

// ---------------- fused W pre-pack + workspace zero ----------------
// blocks [0,192): pack 3 matrices fp32 -> bf16 (RNE) in MFMA B-frag order
// blocks [192,...): zero counts/gs/ge (50512 ints, contiguous)

__global__ void k_pack_zero(const float* __restrict__ W0, const float* __restrict__ W1,
                            const float* __restrict__ W2, short* __restrict__ base,
                            int* __restrict__ zp, int zn) {
    int bid = blockIdx.x;
    if (bid < 192) {
        int m = bid >> 6;
        int idx = (bid & 63) * 256 + threadIdx.x;   // 0..16383
        const float* W = (m == 0) ? W0 : (m == 1) ? W1 : W2;
        float w = W[idx];
        int k = idx >> 7, n = idx & 127;
        int kt = k >> 5, nt = n >> 4;
        int lane = ((k & 31) >> 3) * 16 + (n & 15);
        int e = k & 7;
        int off = ((kt * 8 + nt) * 64 + lane) * 8 + e;
        base[m * 16384 + off] = (short)bf16_rne(w);
    } else {
        int i = (bid - 192) * 256 + threadIdx.x;
        if (i < zn) zp[i] = 0;
    }
}

// ---------------- degree / CSR build ----------------

__global__ void k_edge_deg(const int* __restrict__ dst, int* __restrict__ counts, int e_cnt) {
    int e = blockIdx.x * 256 + threadIdx.x;
    if (e < e_cnt) atomicAdd(&counts[dst[e]], 1);
}

__global__ void k_scan1(const int* __restrict__ counts, int* __restrict__ rs,
                        int* __restrict__ bsum, float* __restrict__ isd, int n) {
    __shared__ int s[256];
    int tid = threadIdx.x;
    int i = blockIdx.x * 256 + tid;
    int v = (i < n) ? counts[i] : 0;
    if (i < n) isd[i] = rsqrtf((float)v + 1.0f);
    s[tid] = v;
    __syncthreads();
    for (int off = 1; off < 256; off <<= 1) {
        int t = (tid >= off) ? s[tid - off] : 0;
        __syncthreads();
        s[tid] += t;
        __syncthreads();
    }
    int incl = s[tid];
    if (i < n) rs[i] = incl - v;
    if (tid == 255) bsum[blockIdx.x] = incl;
}

__global__ void k_scan2(int* __restrict__ bsum, int nb) {
    __shared__ int s[256];
    int tid = threadIdx.x;
    int v = (tid < nb) ? bsum[tid] : 0;
    s[tid] = v;
    __syncthreads();
    for (int off = 1; off < 256; off <<= 1) {
        int t = (tid >= off) ? s[tid - off] : 0;
        __syncthreads();
        s[tid] += t;
        __syncthreads();
    }
    if (tid < nb) bsum[tid] = s[tid] - v;
}

// scan finalize + pooling bounds + rs[n] = E sentinel
__global__ void k_scan3b(int* __restrict__ rs, const int* __restrict__ bsum,
                         const int* __restrict__ batch, int* __restrict__ gs,
                         int* __restrict__ ge, int n, int e_total) {
    int i = blockIdx.x * 256 + threadIdx.x;
    if (i < n) {
        rs[i] += bsum[blockIdx.x];
        if (i == 0) rs[n] = e_total;
        int b = batch[i];
        if (i == 0 || batch[i - 1] != b) gs[b] = i;
        if (i == n - 1 || batch[i + 1] != b) ge[b] = i + 1;
    }
}

// CSR entry packed: .x = src index, .y = coef bits. counts used as down-cursor.
__global__ void k_fill(const int* __restrict__ src, const int* __restrict__ dst,
                       const float* __restrict__ isd, const int* __restrict__ rs,
                       int* __restrict__ counts, uint2* __restrict__ csr, int e_cnt) {
    int e = blockIdx.x * 256 + threadIdx.x;
    if (e < e_cnt) {
        int s = src[e], d = dst[e];
        int pos = rs[d] + atomicSub(&counts[d], 1) - 1;
        csr[pos] = make_uint2((unsigned)s, __float_as_uint(isd[s] * isd[d]));
    }
}

// ---------------- MFMA GEMM: Y[n,128](bf16) = X[n,128] @ W[128,128] (+bias) --
// 256 threads = 4 waves, each wave 32 rows (2 A-frags share each B-load).
// IN_F32: X is fp32 (convert to bf16 RNE in-flight); else X already bf16.

template <int IN_F32>
__global__ __launch_bounds__(256) void k_gemm_mfma(
    const float* __restrict__ Xf, const unsigned short* __restrict__ Xh,
    const short* __restrict__ Wpk, const float* __restrict__ bias,
    unsigned short* __restrict__ Y, int n)
{
    int wid = threadIdx.x >> 6;
    int lane = threadIdx.x & 63;
    int r0 = blockIdx.x * 128 + wid * 32;
    int a0 = r0 + (lane & 15);      if (a0 >= n) a0 = n - 1;
    int a1 = r0 + 16 + (lane & 15); if (a1 >= n) a1 = n - 1;
    int ko = (lane >> 4) * 8;       // k offset within 32-k tile

    const short8* WH = (const short8*)Wpk;

    f32x4 acc0[8], acc1[8];
    f32x4 zero = {0.f, 0.f, 0.f, 0.f};
#pragma unroll
    for (int t = 0; t < 8; ++t) { acc0[t] = zero; acc1[t] = zero; }

#pragma unroll
    for (int kt = 0; kt < 4; ++kt) {
        int k0 = kt * 32 + ko;
        short8 af0, af1;
        if (IN_F32) {
            const float* p0 = Xf + (size_t)a0 * 128 + k0;
            const float* p1 = Xf + (size_t)a1 * 128 + k0;
            float4 u0 = *(const float4*)p0, u1 = *(const float4*)(p0 + 4);
            float4 v0 = *(const float4*)p1, v1 = *(const float4*)(p1 + 4);
            float us[8] = {u0.x, u0.y, u0.z, u0.w, u1.x, u1.y, u1.z, u1.w};
            float vs[8] = {v0.x, v0.y, v0.z, v0.w, v1.x, v1.y, v1.z, v1.w};
#pragma unroll
            for (int i = 0; i < 8; ++i) {
                af0[i] = (short)bf16_rne(us[i]);
                af1[i] = (short)bf16_rne(vs[i]);
            }
        } else {
            af0 = *(const short8*)(Xh + (size_t)a0 * 128 + k0);
            af1 = *(const short8*)(Xh + (size_t)a1 * 128 + k0);
        }
#pragma unroll
        for (int t = 0; t < 8; ++t) {
            short8 bh = WH[(kt * 8 + t) * 64 + lane];
            acc0[t] = __builtin_amdgcn_mfma_f32_16x16x32_bf16(af0, bh, acc0[t], 0, 0, 0);
            acc1[t] = __builtin_amdgcn_mfma_f32_16x16x32_bf16(af1, bh, acc1[t], 0, 0, 0);
        }
    }

    // C/D layout: col = t*16 + (lane&15), row = base + (lane>>4)*4 + reg
    int rbase = r0 + (lane >> 4) * 4;
    int col0 = lane & 15;
#pragma unroll
    for (int t = 0; t < 8; ++t) {
        int col = t * 16 + col0;
        float badd = bias ? bias[col] : 0.f;
#pragma unroll
        for (int r = 0; r < 4; ++r) {
            int row0 = rbase + r;
            int row1 = rbase + 16 + r;
            if (row0 < n) Y[(size_t)row0 * 128 + col] = bf16_rne(acc0[t][r] + badd);
            if (row1 < n) Y[(size_t)row1 * 128 + col] = bf16_rne(acc1[t][r] + badd);
        }
    }
}

// ---------------- aggregation (one 64-lane wave per node, bf16 in/out) ------
// OUT[v] = leaky( sum_e coef_e * HT[src_e] + HT[v]*invdeg[v] + bias )

__global__ __launch_bounds__(256) void k_agg(const unsigned short* __restrict__ HT,
                                             const uint2* __restrict__ csr,
                                             const int* __restrict__ rs,
                                             const float* __restrict__ isd,
                                             const float* __restrict__ bias,
                                             unsigned short* __restrict__ OUT, int n) {
    int node = blockIdx.x * 4 + (threadIdx.x >> 6);
    int lane = threadIdx.x & 63;
    if (node >= n) return;
    const unsigned int* H = (const unsigned int*)HT;   // row = 64 uints (2 bf16)
    int s0 = rs[node];
    int cnt = rs[node + 1] - s0;

    float is = isd[node];
    unsigned int su = H[(size_t)node * 64 + lane];
    float2 b = ((const float2*)bias)[lane];

    float acc0 = 0.f, acc1 = 0.f, acc2 = 0.f, acc3 = 0.f;
    int j = 0;
    for (; j + 8 <= cnt; j += 8) {
        uint2 e[8];
#pragma unroll
        for (int q = 0; q < 8; ++q) e[q] = csr[s0 + j + q];
        unsigned int v[8];
#pragma unroll
        for (int q = 0; q < 8; ++q) v[q] = H[(size_t)e[q].x * 64 + lane];
#pragma unroll
        for (int q = 0; q < 8; ++q) {
            float c = __uint_as_float(e[q].y);
            float f0 = __uint_as_float(v[q] << 16);
            float f1 = __uint_as_float(v[q] & 0xFFFF0000u);
            if (q & 1) { acc2 += f0 * c; acc3 += f1 * c; }
            else       { acc0 += f0 * c; acc1 += f1 * c; }
        }
    }
    for (; j + 4 <= cnt; j += 4) {
        uint2 e[4];
#pragma unroll
        for (int q = 0; q < 4; ++q) e[q] = csr[s0 + j + q];
        unsigned int v[4];
#pragma unroll
        for (int q = 0; q < 4; ++q) v[q] = H[(size_t)e[q].x * 64 + lane];
#pragma unroll
        for (int q = 0; q < 4; ++q) {
            float c = __uint_as_float(e[q].y);
            float f0 = __uint_as_float(v[q] << 16);
            float f1 = __uint_as_float(v[q] & 0xFFFF0000u);
            if (q & 1) { acc2 += f0 * c; acc3 += f1 * c; }
            else       { acc0 += f0 * c; acc1 += f1 * c; }
        }
    }
    for (; j < cnt; ++j) {
        uint2 e = csr[s0 + j];
        unsigned int v = H[(size_t)e.x * 64 + lane];
        float c = __uint_as_float(e.y);
        acc0 += __uint_as_float(v << 16) * c;
        acc1 += __uint_as_float(v & 0xFFFF0000u) * c;
    }

    float invd = is * is;
    float sv0 = __uint_as_float(su << 16);
    float sv1 = __uint_as_float(su & 0xFFFF0000u);
    float ox = acc0 + acc2 + sv0 * invd + b.x;
    float oy = acc1 + acc3 + sv1 * invd + b.y;
    ox = ox > 0.f ? ox : ox * NEG;
    oy = oy > 0.f ? oy : oy * NEG;
    unsigned int pk = (unsigned int)bf16_rne(ox) | ((unsigned int)bf16_rne(oy) << 16);
    ((unsigned int*)OUT)[(size_t)node * 64 + lane] = pk;
}

// ---------------- fused pool + L2-normalize + MLP head (bf16 in) ------------

__global__ __launch_bounds__(256) void k_pool_final(const unsigned short* __restrict__ Hn,
                                                    const int* __restrict__ gs,
                                                    const int* __restrict__ ge,
                                                    const float* __restrict__ W2,
                                                    const float* __restrict__ b2,
                                                    const float* __restrict__ W3,
                                                    const float* __restrict__ b3,
                                                    float* __restrict__ out) {
    __shared__ float part[4][128];
    __shared__ float red[128];
    __shared__ float h1[128];
    int g = blockIdx.x, tid = threadIdx.x;
    int c2 = tid & 63, rr = tid >> 6;   // 4 rows per iter, one uint (2 ch) per thread
    int s = gs[g], e = ge[g];
    const unsigned int* H = (const unsigned int*)Hn;
    float2 acc = make_float2(0.f, 0.f);
    for (int r = s + rr; r < e; r += 4) {
        unsigned int v = H[(size_t)r * 64 + c2];
        acc.x += __uint_as_float(v << 16);
        acc.y += __uint_as_float(v & 0xFFFF0000u);
    }
    part[rr][c2 * 2] = acc.x;
    part[rr][c2 * 2 + 1] = acc.y;
    __syncthreads();
    float mean = 0.f;
    if (tid < 128) {
        mean = (part[0][tid] + part[1][tid] + part[2][tid] + part[3][tid])
               / fmaxf((float)(e - s), 1.f);
        red[tid] = mean * mean;
    }
    __syncthreads();
    for (int off = 64; off > 0; off >>= 1) {
        if (tid < off) red[tid] += red[tid + off];
        __syncthreads();
    }
    if (tid < 128) {
        float norm = sqrtf(red[0]);
        part[0][tid] = mean / fmaxf(norm, 1e-12f);
    }
    __syncthreads();
    if (tid < 128) {
        float a = b2[tid];
#pragma unroll 8
        for (int k = 0; k < 128; ++k) a += part[0][k] * W2[k * 128 + tid];
        a = a > 0.f ? a : a * NEG;
        h1[tid] = a;
    }
    __syncthreads();
    if (tid < DOUT) {
        float a2 = b3[tid];
#pragma unroll 8
        for (int k = 0; k < 128; ++k) a2 += h1[k] * W3[k * DOUT + tid];
        out[g * DOUT + tid] = a2;
    }
}

// ---------------- launch ----------------

extern "C" void kernel_launch(void* const* d_in, const int* in_sizes, int n_in,
                              void* d_out, int out_size, void* d_ws, size_t ws_size,
                              hipStream_t stream) {
    const float* x      = (const float*)d_in[0];
    const int*   ei     = (const int*)d_in[1];   // [2, E] flat
    const int*   batch  = (const int*)d_in[2];
    const float* W_fc1  = (const float*)d_in[3];
    const float* b_fc1  = (const float*)d_in[4];
    const float* W_gc1  = (const float*)d_in[5];
    const float* b_gc1  = (const float*)d_in[6];
    const float* W_gc2  = (const float*)d_in[7];
    const float* b_gc2  = (const float*)d_in[8];
    const float* W_fc2  = (const float*)d_in[9];
    const float* b_fc2  = (const float*)d_in[10];
    const float* W_fc3  = (const float*)d_in[11];
    const float* b_fc3  = (const float*)d_in[12];
    float* out = (float*)d_out;

    const int N = N_NODES, E = N_EDGES;
    const int* e_src = ei;
    const int* e_dst = ei + E;

    // workspace layout (bytes):
    //   H0:     0          12,800,000   (bf16 node features, ping)
    //   H1:     12800000   12,800,000   (bf16 node features, pong)
    //   isd:    25600000      200,000
    //   csr:    25800000    4,800,000
    //   rs:     30600000      200,448   (N+1 ints, padded)
    //   bsum:   30800448        1,024
    //   counts: 30801472      200,000   -- zero region start
    //   gs:     31001472        1,024
    //   ge:     31002496        1,024   -- zero region end
    //   Wpk:    31003520       98,304   (3 mats x 16384 bf16)
    // total: 31,101,824
    char* ws = (char*)d_ws;
    unsigned short* H0     = (unsigned short*)(ws + 0);
    unsigned short* H1     = (unsigned short*)(ws + 12800000);
    float*          isd    = (float*)(ws + 25600000);
    uint2*          csr    = (uint2*)(ws + 25800000);
    int*            rs     = (int*)  (ws + 30600000);
    int*            bsum   = (int*)  (ws + 30800448);
    int*            counts = (int*)  (ws + 30801472);
    int*            gs     = (int*)  (ws + 31001472);
    int*            ge     = (int*)  (ws + 31002496);
    short*          Wpk    = (short*)(ws + 31003520);

    const int ZN = 50000 + 256 + 256;           // counts,gs,ge contiguous
    const int NB = (N + 255) / 256;             // 196
    const int EB = (E + 255) / 256;
    const int ZB = (ZN + 255) / 256;            // 198

    k_pack_zero<<<192 + ZB, 256, 0, stream>>>(W_fc1, W_gc1, W_gc2, Wpk, counts, ZN);
    k_edge_deg<<<EB, 256, 0, stream>>>(e_dst, counts, E);
    k_scan1<<<NB, 256, 0, stream>>>(counts, rs, bsum, isd, N);
    k_scan2<<<1, 256, 0, stream>>>(bsum, NB);
    k_scan3b<<<NB, 256, 0, stream>>>(rs, bsum, batch, gs, ge, N, E);
    k_fill<<<EB, 256, 0, stream>>>(e_src, e_dst, isd, rs, counts, csr, E);

    const int GB = (N + 127) / 128;             // 391
    // hx = x @ W_fc1 + b_fc1   (fp32 in -> bf16 H0)
    k_gemm_mfma<1><<<GB, 256, 0, stream>>>(x, nullptr, Wpk, b_fc1, H0, N);
    // conv1: ht = H0 @ W_gc1 -> H1 ; agg -> H0
    k_gemm_mfma<0><<<GB, 256, 0, stream>>>(nullptr, H0, Wpk + 16384, nullptr, H1, N);
    k_agg<<<(N + 3) / 4, 256, 0, stream>>>(H1, csr, rs, isd, b_gc1, H0, N);
    // conv2: ht = H0 @ W_gc2 -> H1 ; agg -> H0
    k_gemm_mfma<0><<<GB, 256, 0, stream>>>(nullptr, H0, Wpk + 32768, nullptr, H1, N);
    k_agg<<<(N + 3) / 4, 256, 0, stream>>>(H1, csr, rs, isd, b_gc2, H0, N);

    // pool + normalize + MLP head (fused)
    k_pool_final<<<N_GRAPHS, 256, 0, stream>>>(H0, gs, ge, W_fc2, b_fc2, W_fc3, b_fc3, out);

    (void)in_sizes; (void)n_in; (void)out_size; (void)ws_size;
}